// Round 8
// baseline (284.305 us; speedup 1.0000x reference)
//
#include <hip/hip_runtime.h>
#include <hip/hip_bf16.h>

// B=4, C=2048, D=1024. f32 inputs, f32 output. bf16 MFMA internally.
// R8: QKV on 256^2 8-phase; S-GEMM moved to 128^2 causal-skip (occupancy);
// PV on 128^2 K-causal longest-first; 64x64 vectorized V-transpose; fused
// W-transpose (z-grid); prefix-IO softmax.

typedef __attribute__((ext_vector_type(8))) __bf16 bf16x8;
typedef __attribute__((ext_vector_type(4))) float f32x4;
typedef __attribute__((ext_vector_type(4))) float float4v;
typedef __attribute__((ext_vector_type(4))) unsigned int uint4v;
typedef __attribute__((ext_vector_type(4))) unsigned short ushort4v;

#define GLL16(gp, lp)                                                        \
  __builtin_amdgcn_global_load_lds(                                          \
      (const __attribute__((address_space(1))) void*)(gp),                   \
      (__attribute__((address_space(3))) void*)(lp), 16, 0, 0)

#define BAR()  __builtin_amdgcn_s_barrier()
#define SB0()  __builtin_amdgcn_sched_barrier(0)
#define WLG0() asm volatile("s_waitcnt lgkmcnt(0)" ::: "memory")
#define WVM4() asm volatile("s_waitcnt vmcnt(4)" ::: "memory")
#define WVM0() asm volatile("s_waitcnt vmcnt(0)" ::: "memory")
#define PRIO(n) __builtin_amdgcn_s_setprio(n)

__device__ __forceinline__ unsigned short f2b(float f) {
  union { float f; unsigned u; } v; v.f = f;
  unsigned r = v.u + 0x7FFF + ((v.u >> 16) & 1);
  return (unsigned short)(r >> 16);
}
__device__ __forceinline__ float b2f(unsigned short h) {
  union { unsigned u; float f; } v; v.u = ((unsigned)h) << 16;
  return v.f;
}
__device__ __forceinline__ void store_out(unsigned short* p, float v) { *p = f2b(v); }
__device__ __forceinline__ void store_out(float* p, float v) { *p = v; }

// ---- x f32 -> bf16 ----
__global__ __launch_bounds__(256) void k_convert(const float* __restrict__ in,
                                                 unsigned short* __restrict__ out, long n) {
  long i = ((long)blockIdx.x * 256 + threadIdx.x) * 4;
  if (i + 3 < n) {
    float4v v = *reinterpret_cast<const float4v*>(in + i);
    ushort4v o;
    o.x = f2b(v.x); o.y = f2b(v.y); o.z = f2b(v.z); o.w = f2b(v.w);
    *reinterpret_cast<ushort4v*>(out + i) = o;
  }
}

// ---- W_{q,k,v} (1024x1024 f32) -> Wt (bf16, transposed), fused over z ----
__global__ __launch_bounds__(256) void k_transpose_w3(const float* __restrict__ Wq,
                                                      const float* __restrict__ Wk,
                                                      const float* __restrict__ Wv,
                                                      unsigned short* __restrict__ out) {
  __shared__ float t[32][33];
  const float* in = blockIdx.z == 0 ? Wq : (blockIdx.z == 1 ? Wk : Wv);
  unsigned short* o = out + (long)blockIdx.z * 1048576;
  int tx = threadIdx.x & 31, ty = threadIdx.x >> 5;
  int c0 = blockIdx.x * 32, r0 = blockIdx.y * 32;
  for (int i = ty; i < 32; i += 8)
    t[i][tx] = in[(long)(r0 + i) * 1024 + c0 + tx];
  __syncthreads();
  for (int i = ty; i < 32; i += 8)
    o[(long)(c0 + i) * 1024 + r0 + tx] = f2b(t[tx][i]);
}

// ---- V (per-batch R x Cc bf16) -> Vt (Cc x R bf16), 64x64 tiles, ushort4 IO ----
__global__ __launch_bounds__(256) void k_transpose_v(const unsigned short* __restrict__ in,
                                                     unsigned short* __restrict__ out,
                                                     int R, int Cc) {
  __shared__ unsigned short t[64][68];
  long base = (long)blockIdx.z * (long)R * Cc;
  int c0 = blockIdx.x * 64, r0 = blockIdx.y * 64;
  int tid = threadIdx.x;
  int a = tid >> 4;          // 0..15
  int g4 = (tid & 15) * 4;   // 4-elem group
#pragma unroll
  for (int it = 0; it < 4; ++it) {
    int i = a + it * 16;
    *reinterpret_cast<ushort4v*>(&t[i][g4]) =
        *reinterpret_cast<const ushort4v*>(&in[base + (long)(r0 + i) * Cc + c0 + g4]);
  }
  __syncthreads();
#pragma unroll
  for (int it = 0; it < 4; ++it) {
    int c = a + it * 16;
    ushort4v v;
    v.x = t[g4 + 0][c]; v.y = t[g4 + 1][c]; v.z = t[g4 + 2][c]; v.w = t[g4 + 3][c];
    *reinterpret_cast<ushort4v*>(&out[base + (long)(c0 + c) * R + r0 + g4]) = v;
  }
}

// ==== 256x256x64 8-phase MFMA GEMM (R6/R7-verified) ====
#define RDA(buf, half)                                                        \
  _Pragma("unroll") for (int m_ = 0; m_ < 4; ++m_)                            \
  _Pragma("unroll") for (int ks_ = 0; ks_ < 2; ++ks_)                         \
    af[m_][ks_] = *reinterpret_cast<const bf16x8*>(                           \
        (buf) + (arb + (half) * 4 + m_) * 1024 + ks_ * 512 + foff);

#define RDB(buf, half, BF)                                                    \
  _Pragma("unroll") for (int n_ = 0; n_ < 2; ++n_)                            \
  _Pragma("unroll") for (int ks_ = 0; ks_ < 2; ++ks_)                         \
    BF[n_][ks_] = *reinterpret_cast<const bf16x8*>(                           \
        (buf) + (brb + (half) * 2 + n_) * 1024 + ks_ * 512 + foff);

#define QUAD(mh, nh, BF)                                                      \
  _Pragma("unroll") for (int m_ = 0; m_ < 4; ++m_)                            \
  _Pragma("unroll") for (int n_ = 0; n_ < 2; ++n_)                            \
  _Pragma("unroll") for (int ks_ = 0; ks_ < 2; ++ks_)                         \
    acc[(mh) * 4 + m_][(nh) * 2 + n_] =                                       \
        __builtin_amdgcn_mfma_f32_16x16x32_bf16(                              \
            af[m_][ks_], BF[n_][ks_], acc[(mh) * 4 + m_][(nh) * 2 + n_], 0, 0, 0);

#define STGA(buf, h, k0)                                                      \
  GLL16(gA + (long)(128 * (h)) * K + (k0),      (buf) + (16 * (h) + wave) * 512); \
  GLL16(gA + (long)(128 * (h) + 64) * K + (k0), (buf) + (16 * (h) + 8 + wave) * 512);

#define STGB(buf, h, k0)                                                      \
  GLL16(gB + (long)(128 * (h)) * K + (k0),      (buf) + (16 * (h) + wave) * 512); \
  GLL16(gB + (long)(128 * (h) + 64) * K + (k0), (buf) + (16 * (h) + 8 + wave) * 512);

template <typename OutT, bool CAUSAL_SKIP, bool KCAUSAL>
__global__ __launch_bounds__(512, 2) void k_gemm256(
    const unsigned short* __restrict__ A, const unsigned short* __restrict__ Bt,
    OutT* __restrict__ C, int M, int N, int K, float scale,
    long sA, long sB, long sC) {
  constexpr int BM = 256;
  __shared__ __align__(16) unsigned short lds[65536];  // 128 KB
  unsigned short* const lA0 = lds;
  unsigned short* const lA1 = lds + 16384;
  unsigned short* const lB0 = lds + 32768;
  unsigned short* const lB1 = lds + 49152;

  const int bm = blockIdx.x, bn = blockIdx.y;
  if (CAUSAL_SKIP && bn > bm) return;
  const long z = blockIdx.z;
  A += z * sA; Bt += z * sB; C += z * sC;

  const int tid = threadIdx.x;
  const int lane = tid & 63, wave = tid >> 6;
  const int row0 = bm * BM, col0 = bn * 256;

  const int kend = KCAUSAL ? min(K, (bm + 1) * BM) : K;
  const int niter = kend >> 7;

  const int scol = ((lane & 3) * 8) ^ ((lane & 32) ? 16 : 0);
  const int srowi = (wave >> 1) * 16 + (lane >> 2);
  const int scolw = (wave & 1) * 32 + scol;
  const unsigned short* gA = A + (long)(row0 + srowi) * K + scolw;
  const unsigned short* gB = Bt + (long)(col0 + srowi) * K + scolw;

  const int foff = ((lane & 15) * 32 + (lane >> 4) * 8) ^ ((lane & 8) ? 16 : 0);
  const int arb = 8 * (wave >> 2);
  const int brb = 4 * (wave & 3);

  bf16x8 af[4][2], bf0[2][2], bf1[2][2];
  f32x4 acc[8][4] = {};

  STGA(lA0, 0, 0); STGA(lA0, 1, 0);
  STGB(lB0, 0, 0); STGB(lB0, 1, 0);
  STGB(lB1, 0, 64); STGA(lA1, 0, 64);
  WVM4();
  BAR(); SB0();

  for (int j = 0; j < niter; ++j) {
    const bool last = (j == niter - 1);
    const int kb = j * 128;
    // P1
    RDA(lA0, 0); RDB(lB0, 0, bf0);
    STGA(lA1, 1, kb + 64);
    BAR(); WLG0(); SB0();
    PRIO(1); QUAD(0, 0, bf0); PRIO(0);
    BAR(); SB0();
    // P2
    RDB(lB0, 1, bf1);
    STGB(lB1, 1, kb + 64);
    BAR(); WLG0(); SB0();
    PRIO(1); QUAD(0, 1, bf1); PRIO(0);
    BAR(); SB0();
    // P3
    RDA(lA0, 1);
    if (!last) { STGB(lB0, 0, kb + 128); }
    BAR(); WLG0(); SB0();
    PRIO(1); QUAD(1, 1, bf1); PRIO(0);
    BAR(); SB0();
    // P4
    if (!last) { STGA(lA0, 0, kb + 128); }
    BAR();
    if (!last) { WVM4(); } else { WVM0(); }
    SB0();
    PRIO(1); QUAD(1, 0, bf0); PRIO(0);
    BAR(); SB0();
    // P5
    RDA(lA1, 0); RDB(lB1, 0, bf0);
    if (!last) { STGA(lA0, 1, kb + 128); }
    BAR(); WLG0(); SB0();
    PRIO(1); QUAD(0, 0, bf0); PRIO(0);
    BAR(); SB0();
    // P6
    RDB(lB1, 1, bf1);
    if (!last) { STGB(lB0, 1, kb + 128); }
    BAR(); WLG0(); SB0();
    PRIO(1); QUAD(0, 1, bf1); PRIO(0);
    BAR(); SB0();
    // P7
    RDA(lA1, 1);
    if (!last) { STGB(lB1, 0, kb + 192); }
    BAR(); WLG0(); SB0();
    PRIO(1); QUAD(1, 1, bf1); PRIO(0);
    BAR(); SB0();
    // P8
    if (!last) { STGA(lA1, 0, kb + 192); }
    BAR();
    if (!last) { WVM4(); }
    SB0();
    PRIO(1); QUAD(1, 0, bf0); PRIO(0);
    BAR(); SB0();
  }

  const int or0 = row0 + (wave >> 2) * 128 + (lane >> 4) * 4;
  const int oc0 = col0 + (wave & 3) * 64 + (lane & 15);
#pragma unroll
  for (int mm = 0; mm < 8; ++mm)
#pragma unroll
    for (int nn = 0; nn < 4; ++nn)
#pragma unroll
      for (int jj = 0; jj < 4; ++jj) {
        long idx = (long)(or0 + mm * 16 + jj) * N + (oc0 + nn * 16);
        store_out(&C[idx], acc[mm][nn][jj] * scale);
      }
}

// ==== 128x128x32 m97-structure GEMM; CSKIP (bn>bm exit) and/or K-causal ====
template <typename OutT, bool CAUSAL_SKIP, bool KCAUSAL, bool REVERSE_X>
__global__ __launch_bounds__(256) void k_gemm128(const unsigned short* __restrict__ A,
                                                 const unsigned short* __restrict__ Bt,
                                                 OutT* __restrict__ C,
                                                 int M, int N, int K, float scale,
                                                 long sA, long sB, long sC) {
  constexpr int BM = 128, BK = 32;
  __shared__ unsigned short As[128 * 32];
  __shared__ unsigned short Bs[128 * 32];
  const int bm = REVERSE_X ? (gridDim.x - 1 - blockIdx.x) : blockIdx.x;
  const int bn = blockIdx.y;
  if (CAUSAL_SKIP && bn > bm) return;
  const long z = blockIdx.z;
  A += z * sA; Bt += z * sB; C += z * sC;

  int tid = threadIdx.x;
  int lane = tid & 63, wave = tid >> 6;
  int wr = (wave >> 1) * 64, wc = (wave & 1) * 64;
  int lr = lane & 15;
  int lk = (lane >> 4) * 8;

  int kend = KCAUSAL ? min(K, (bm + 1) * BM) : K;

  int srow = 32 * wave + (lane >> 2);
  int scol = (lane & 3) * 8;
  const unsigned short* gA = A + (long)(bm * BM + srow) * K + scol;
  const unsigned short* gB = Bt + (long)(bn * 128 + srow) * K + scol;
  const long rowK16 = 16L * (long)K;
  unsigned short* lA = &As[(32 * wave) * 32];
  unsigned short* lB = &Bs[(32 * wave) * 32];

  f32x4 acc[4][4] = {};

  for (int k0 = 0; k0 < kend; k0 += BK) {
    GLL16(gA + k0,          lA);
    GLL16(gA + k0 + rowK16, lA + 16 * 32);
    GLL16(gB + k0,          lB);
    GLL16(gB + k0 + rowK16, lB + 16 * 32);
    __syncthreads();

    bf16x8 af[4], bfr[4];
#pragma unroll
    for (int m = 0; m < 4; ++m)
      af[m] = *reinterpret_cast<const bf16x8*>(&As[(wr + m * 16 + lr) * 32 + lk]);
#pragma unroll
    for (int n = 0; n < 4; ++n)
      bfr[n] = *reinterpret_cast<const bf16x8*>(&Bs[(wc + n * 16 + lr) * 32 + lk]);
#pragma unroll
    for (int m = 0; m < 4; ++m)
#pragma unroll
      for (int n = 0; n < 4; ++n)
        acc[m][n] = __builtin_amdgcn_mfma_f32_16x16x32_bf16(af[m], bfr[n], acc[m][n], 0, 0, 0);
    __syncthreads();
  }

  int orow0 = bm * BM + wr + (lane >> 4) * 4;
  int ocol0 = bn * 128 + wc + lr;
#pragma unroll
  for (int m = 0; m < 4; ++m)
#pragma unroll
    for (int n = 0; n < 4; ++n)
#pragma unroll
      for (int j = 0; j < 4; ++j) {
        long idx = (long)(orow0 + m * 16 + j) * N + (ocol0 + n * 16);
        store_out(&C[idx], acc[m][n][j] * scale);
      }
}

// ---- single-pass causal row softmax, prefix IO (cols < (r|127)+1 only) ----
__global__ __launch_bounds__(256) void k_softmax(unsigned short* __restrict__ S, int Cc) {
  long row = blockIdx.x;
  unsigned short* s = S + row * (long)Cc;
  int r = (int)(row & (Cc - 1));
  int n = r + 1;
  int ktile = (r | 127) + 1;  // PV reads only cols < ktile
  int tid = threadIdx.x;
  int lane = tid & 63, wv = tid >> 6;
  int c0 = tid * 8;
  bool act = c0 < ktile;
  __shared__ float redm[4], reds[4];

  uint4v raw = {0, 0, 0, 0};
  if (act) raw = *reinterpret_cast<const uint4v*>(s + c0);
  float f[8];
#pragma unroll
  for (int i = 0; i < 4; ++i) {
    f[2 * i]     = b2f((unsigned short)(raw[i] & 0xFFFF));
    f[2 * i + 1] = b2f((unsigned short)(raw[i] >> 16));
  }

  float mx = -3.0e38f;
#pragma unroll
  for (int i = 0; i < 8; ++i)
    if (c0 + i < n) mx = fmaxf(mx, f[i]);
#pragma unroll
  for (int o = 32; o > 0; o >>= 1) mx = fmaxf(mx, __shfl_xor(mx, o, 64));
  if (lane == 0) redm[wv] = mx;
  __syncthreads();
  mx = fmaxf(fmaxf(redm[0], redm[1]), fmaxf(redm[2], redm[3]));

  float e[8];
  float sum = 0.f;
#pragma unroll
  for (int i = 0; i < 8; ++i) {
    e[i] = (c0 + i < n) ? __expf(f[i] - mx) : 0.f;
    sum += e[i];
  }
#pragma unroll
  for (int o = 32; o > 0; o >>= 1) sum += __shfl_xor(sum, o, 64);
  if (lane == 0) reds[wv] = sum;
  __syncthreads();
  sum = reds[0] + reds[1] + reds[2] + reds[3];
  float inv = 1.0f / sum;

  if (act) {
    uint4v out;
#pragma unroll
    for (int i = 0; i < 4; ++i) {
      unsigned lo = f2b(e[2 * i] * inv);
      unsigned hi = f2b(e[2 * i + 1] * inv);
      out[i] = lo | (hi << 16);
    }
    *reinterpret_cast<uint4v*>(s + c0) = out;
  }
}

extern "C" void kernel_launch(void* const* d_in, const int* in_sizes, int n_in,
                              void* d_out, int out_size, void* d_ws, size_t ws_size,
                              hipStream_t stream) {
  const int B = 4, C = 2048, D = 1024;
  const long MB = (long)B * C;  // 8192 rows

  const float* x  = (const float*)d_in[0];
  const float* Wq = (const float*)d_in[1];
  const float* Wk = (const float*)d_in[2];
  const float* Wv = (const float*)d_in[3];
  float* out = (float*)d_out;
  char* ws = (char*)d_ws;

  unsigned short* S   = (unsigned short*)(ws);
  unsigned short* Xb  = (unsigned short*)(ws);
  unsigned short* Wt  = (unsigned short*)(ws + 16777216);
  unsigned short* QKV = (unsigned short*)(ws + 33554432);
  unsigned short* Vt  = (unsigned short*)(ws + 83886080);
  unsigned short* Q  = QKV;
  unsigned short* Kk = QKV + MB * D;
  unsigned short* V  = QKV + 2L * MB * D;

  // 1. x -> bf16
  k_convert<<<8192, 256, 0, stream>>>(x, Xb, MB * D);

  // 2. W -> Wt (bf16, transposed), one launch
  k_transpose_w3<<<dim3(32, 32, 3), 256, 0, stream>>>(Wq, Wk, Wv, Wt);

  // 3. QKV = Xb @ Wt^T  (256^2 8-phase)
  k_gemm256<unsigned short, false, false><<<dim3(32, 4, 3), 512, 0, stream>>>(
      Xb, Wt, QKV, (int)MB, D, D, 1.0f, 0L, (long)D * D, MB * D);

  // 4. Vt[b] = V[b]^T  (64x64 vectorized)
  k_transpose_v<<<dim3(16, 32, 4), 256, 0, stream>>>(V, Vt, C, D);

  // 5. S[b] = Q[b] @ K[b]^T / 32  (128^2, causal tile skip, fine-grained)
  k_gemm128<unsigned short, true, false, false><<<dim3(16, 16, 4), 256, 0, stream>>>(
      Q, Kk, S, C, C, D, 1.0f / 32.0f, (long)C * D, (long)C * D, (long)C * C);

  // 6. causal softmax rows, in place (single pass, prefix IO)
  k_softmax<<<B * C, 256, 0, stream>>>(S, C);

  // 7. out[b] = P[b] @ Vt[b]^T  (128^2, K-causal, longest-first)
  k_gemm128<float, false, true, true><<<dim3(16, 8, 4), 256, 0, stream>>>(
      S, Vt, out, C, D, C, 1.0f, (long)C * C, (long)D * C, (long)C * D);
}

// Round 12
// 264.521 us; speedup vs baseline: 1.0748x; 1.0748x over previous
//
#include <hip/hip_runtime.h>
#include <hip/hip_bf16.h>

// B=4, C=2048, D=1024. f32 inputs, f32 output. bf16 MFMA internally.
// R9: bisect-revert of R8's regression. S-GEMM back to 256^2 8-phase (R7),
// transpose_v back to 32x32 conflict-free (R7). Kept from R8: fused
// W-transpose (tw3), prefix-IO softmax. QKV 256^2 8-phase; PV 128^2
// K-causal longest-first.

typedef __attribute__((ext_vector_type(8))) __bf16 bf16x8;
typedef __attribute__((ext_vector_type(4))) float f32x4;
typedef __attribute__((ext_vector_type(4))) float float4v;
typedef __attribute__((ext_vector_type(4))) unsigned int uint4v;
typedef __attribute__((ext_vector_type(4))) unsigned short ushort4v;

#define GLL16(gp, lp)                                                        \
  __builtin_amdgcn_global_load_lds(                                          \
      (const __attribute__((address_space(1))) void*)(gp),                   \
      (__attribute__((address_space(3))) void*)(lp), 16, 0, 0)

#define BAR()  __builtin_amdgcn_s_barrier()
#define SB0()  __builtin_amdgcn_sched_barrier(0)
#define WLG0() asm volatile("s_waitcnt lgkmcnt(0)" ::: "memory")
#define WVM4() asm volatile("s_waitcnt vmcnt(4)" ::: "memory")
#define WVM0() asm volatile("s_waitcnt vmcnt(0)" ::: "memory")
#define PRIO(n) __builtin_amdgcn_s_setprio(n)

__device__ __forceinline__ unsigned short f2b(float f) {
  union { float f; unsigned u; } v; v.f = f;
  unsigned r = v.u + 0x7FFF + ((v.u >> 16) & 1);
  return (unsigned short)(r >> 16);
}
__device__ __forceinline__ float b2f(unsigned short h) {
  union { unsigned u; float f; } v; v.u = ((unsigned)h) << 16;
  return v.f;
}
__device__ __forceinline__ void store_out(unsigned short* p, float v) { *p = f2b(v); }
__device__ __forceinline__ void store_out(float* p, float v) { *p = v; }

// ---- x f32 -> bf16 ----
__global__ __launch_bounds__(256) void k_convert(const float* __restrict__ in,
                                                 unsigned short* __restrict__ out, long n) {
  long i = ((long)blockIdx.x * 256 + threadIdx.x) * 4;
  if (i + 3 < n) {
    float4v v = *reinterpret_cast<const float4v*>(in + i);
    ushort4v o;
    o.x = f2b(v.x); o.y = f2b(v.y); o.z = f2b(v.z); o.w = f2b(v.w);
    *reinterpret_cast<ushort4v*>(out + i) = o;
  }
}

// ---- W_{q,k,v} (1024x1024 f32) -> Wt (bf16, transposed), fused over z ----
__global__ __launch_bounds__(256) void k_transpose_w3(const float* __restrict__ Wq,
                                                      const float* __restrict__ Wk,
                                                      const float* __restrict__ Wv,
                                                      unsigned short* __restrict__ out) {
  __shared__ float t[32][33];
  const float* in = blockIdx.z == 0 ? Wq : (blockIdx.z == 1 ? Wk : Wv);
  unsigned short* o = out + (long)blockIdx.z * 1048576;
  int tx = threadIdx.x & 31, ty = threadIdx.x >> 5;
  int c0 = blockIdx.x * 32, r0 = blockIdx.y * 32;
  for (int i = ty; i < 32; i += 8)
    t[i][tx] = in[(long)(r0 + i) * 1024 + c0 + tx];
  __syncthreads();
  for (int i = ty; i < 32; i += 8)
    o[(long)(c0 + i) * 1024 + r0 + tx] = f2b(t[tx][i]);
}

// ---- V (per-batch R x Cc bf16) -> Vt (Cc x R bf16), 32x32 (R7-verified) ----
__global__ __launch_bounds__(256) void k_transpose_v(const unsigned short* __restrict__ in,
                                                     unsigned short* __restrict__ out,
                                                     int R, int Cc) {
  __shared__ unsigned short t[32][33];
  long base = (long)blockIdx.z * (long)R * Cc;
  int tx = threadIdx.x & 31, ty = threadIdx.x >> 5;
  int c0 = blockIdx.x * 32, r0 = blockIdx.y * 32;
  for (int i = ty; i < 32; i += 8)
    t[i][tx] = in[base + (long)(r0 + i) * Cc + c0 + tx];
  __syncthreads();
  for (int i = ty; i < 32; i += 8)
    out[base + (long)(c0 + i) * R + r0 + tx] = t[tx][i];
}

// ==== 256x256x64 8-phase MFMA GEMM (R6/R7-verified) ====
#define RDA(buf, half)                                                        \
  _Pragma("unroll") for (int m_ = 0; m_ < 4; ++m_)                            \
  _Pragma("unroll") for (int ks_ = 0; ks_ < 2; ++ks_)                         \
    af[m_][ks_] = *reinterpret_cast<const bf16x8*>(                           \
        (buf) + (arb + (half) * 4 + m_) * 1024 + ks_ * 512 + foff);

#define RDB(buf, half, BF)                                                    \
  _Pragma("unroll") for (int n_ = 0; n_ < 2; ++n_)                            \
  _Pragma("unroll") for (int ks_ = 0; ks_ < 2; ++ks_)                         \
    BF[n_][ks_] = *reinterpret_cast<const bf16x8*>(                           \
        (buf) + (brb + (half) * 2 + n_) * 1024 + ks_ * 512 + foff);

#define QUAD(mh, nh, BF)                                                      \
  _Pragma("unroll") for (int m_ = 0; m_ < 4; ++m_)                            \
  _Pragma("unroll") for (int n_ = 0; n_ < 2; ++n_)                            \
  _Pragma("unroll") for (int ks_ = 0; ks_ < 2; ++ks_)                         \
    acc[(mh) * 4 + m_][(nh) * 2 + n_] =                                       \
        __builtin_amdgcn_mfma_f32_16x16x32_bf16(                              \
            af[m_][ks_], BF[n_][ks_], acc[(mh) * 4 + m_][(nh) * 2 + n_], 0, 0, 0);

#define STGA(buf, h, k0)                                                      \
  GLL16(gA + (long)(128 * (h)) * K + (k0),      (buf) + (16 * (h) + wave) * 512); \
  GLL16(gA + (long)(128 * (h) + 64) * K + (k0), (buf) + (16 * (h) + 8 + wave) * 512);

#define STGB(buf, h, k0)                                                      \
  GLL16(gB + (long)(128 * (h)) * K + (k0),      (buf) + (16 * (h) + wave) * 512); \
  GLL16(gB + (long)(128 * (h) + 64) * K + (k0), (buf) + (16 * (h) + 8 + wave) * 512);

template <typename OutT, bool CAUSAL_SKIP, bool KCAUSAL>
__global__ __launch_bounds__(512, 2) void k_gemm256(
    const unsigned short* __restrict__ A, const unsigned short* __restrict__ Bt,
    OutT* __restrict__ C, int M, int N, int K, float scale,
    long sA, long sB, long sC) {
  constexpr int BM = 256;
  __shared__ __align__(16) unsigned short lds[65536];  // 128 KB
  unsigned short* const lA0 = lds;
  unsigned short* const lA1 = lds + 16384;
  unsigned short* const lB0 = lds + 32768;
  unsigned short* const lB1 = lds + 49152;

  const int bm = blockIdx.x, bn = blockIdx.y;
  if (CAUSAL_SKIP && bn > bm) return;
  const long z = blockIdx.z;
  A += z * sA; Bt += z * sB; C += z * sC;

  const int tid = threadIdx.x;
  const int lane = tid & 63, wave = tid >> 6;
  const int row0 = bm * BM, col0 = bn * 256;

  const int kend = KCAUSAL ? min(K, (bm + 1) * BM) : K;
  const int niter = kend >> 7;

  const int scol = ((lane & 3) * 8) ^ ((lane & 32) ? 16 : 0);
  const int srowi = (wave >> 1) * 16 + (lane >> 2);
  const int scolw = (wave & 1) * 32 + scol;
  const unsigned short* gA = A + (long)(row0 + srowi) * K + scolw;
  const unsigned short* gB = Bt + (long)(col0 + srowi) * K + scolw;

  const int foff = ((lane & 15) * 32 + (lane >> 4) * 8) ^ ((lane & 8) ? 16 : 0);
  const int arb = 8 * (wave >> 2);
  const int brb = 4 * (wave & 3);

  bf16x8 af[4][2], bf0[2][2], bf1[2][2];
  f32x4 acc[8][4] = {};

  STGA(lA0, 0, 0); STGA(lA0, 1, 0);
  STGB(lB0, 0, 0); STGB(lB0, 1, 0);
  STGB(lB1, 0, 64); STGA(lA1, 0, 64);
  WVM4();
  BAR(); SB0();

  for (int j = 0; j < niter; ++j) {
    const bool last = (j == niter - 1);
    const int kb = j * 128;
    // P1
    RDA(lA0, 0); RDB(lB0, 0, bf0);
    STGA(lA1, 1, kb + 64);
    BAR(); WLG0(); SB0();
    PRIO(1); QUAD(0, 0, bf0); PRIO(0);
    BAR(); SB0();
    // P2
    RDB(lB0, 1, bf1);
    STGB(lB1, 1, kb + 64);
    BAR(); WLG0(); SB0();
    PRIO(1); QUAD(0, 1, bf1); PRIO(0);
    BAR(); SB0();
    // P3
    RDA(lA0, 1);
    if (!last) { STGB(lB0, 0, kb + 128); }
    BAR(); WLG0(); SB0();
    PRIO(1); QUAD(1, 1, bf1); PRIO(0);
    BAR(); SB0();
    // P4
    if (!last) { STGA(lA0, 0, kb + 128); }
    BAR();
    if (!last) { WVM4(); } else { WVM0(); }
    SB0();
    PRIO(1); QUAD(1, 0, bf0); PRIO(0);
    BAR(); SB0();
    // P5
    RDA(lA1, 0); RDB(lB1, 0, bf0);
    if (!last) { STGA(lA0, 1, kb + 128); }
    BAR(); WLG0(); SB0();
    PRIO(1); QUAD(0, 0, bf0); PRIO(0);
    BAR(); SB0();
    // P6
    RDB(lB1, 1, bf1);
    if (!last) { STGB(lB0, 1, kb + 128); }
    BAR(); WLG0(); SB0();
    PRIO(1); QUAD(0, 1, bf1); PRIO(0);
    BAR(); SB0();
    // P7
    RDA(lA1, 1);
    if (!last) { STGB(lB1, 0, kb + 192); }
    BAR(); WLG0(); SB0();
    PRIO(1); QUAD(1, 1, bf1); PRIO(0);
    BAR(); SB0();
    // P8
    if (!last) { STGA(lA1, 0, kb + 192); }
    BAR();
    if (!last) { WVM4(); }
    SB0();
    PRIO(1); QUAD(1, 0, bf0); PRIO(0);
    BAR(); SB0();
  }

  const int or0 = row0 + (wave >> 2) * 128 + (lane >> 4) * 4;
  const int oc0 = col0 + (wave & 3) * 64 + (lane & 15);
#pragma unroll
  for (int mm = 0; mm < 8; ++mm)
#pragma unroll
    for (int nn = 0; nn < 4; ++nn)
#pragma unroll
      for (int jj = 0; jj < 4; ++jj) {
        long idx = (long)(or0 + mm * 16 + jj) * N + (oc0 + nn * 16);
        store_out(&C[idx], acc[mm][nn][jj] * scale);
      }
}

// ==== 128x128x32 m97-structure GEMM (PV only) ====
template <typename OutT, bool KCAUSAL, bool REVERSE_X>
__global__ __launch_bounds__(256) void k_gemm128(const unsigned short* __restrict__ A,
                                                 const unsigned short* __restrict__ Bt,
                                                 OutT* __restrict__ C,
                                                 int M, int N, int K, float scale,
                                                 long sA, long sB, long sC) {
  constexpr int BM = 128, BK = 32;
  __shared__ unsigned short As[128 * 32];
  __shared__ unsigned short Bs[128 * 32];
  const int bm = REVERSE_X ? (gridDim.x - 1 - blockIdx.x) : blockIdx.x;
  const int bn = blockIdx.y;
  const long z = blockIdx.z;
  A += z * sA; Bt += z * sB; C += z * sC;

  int tid = threadIdx.x;
  int lane = tid & 63, wave = tid >> 6;
  int wr = (wave >> 1) * 64, wc = (wave & 1) * 64;
  int lr = lane & 15;
  int lk = (lane >> 4) * 8;

  int kend = KCAUSAL ? min(K, (bm + 1) * BM) : K;

  int srow = 32 * wave + (lane >> 2);
  int scol = (lane & 3) * 8;
  const unsigned short* gA = A + (long)(bm * BM + srow) * K + scol;
  const unsigned short* gB = Bt + (long)(bn * 128 + srow) * K + scol;
  const long rowK16 = 16L * (long)K;
  unsigned short* lA = &As[(32 * wave) * 32];
  unsigned short* lB = &Bs[(32 * wave) * 32];

  f32x4 acc[4][4] = {};

  for (int k0 = 0; k0 < kend; k0 += BK) {
    GLL16(gA + k0,          lA);
    GLL16(gA + k0 + rowK16, lA + 16 * 32);
    GLL16(gB + k0,          lB);
    GLL16(gB + k0 + rowK16, lB + 16 * 32);
    __syncthreads();

    bf16x8 af[4], bfr[4];
#pragma unroll
    for (int m = 0; m < 4; ++m)
      af[m] = *reinterpret_cast<const bf16x8*>(&As[(wr + m * 16 + lr) * 32 + lk]);
#pragma unroll
    for (int n = 0; n < 4; ++n)
      bfr[n] = *reinterpret_cast<const bf16x8*>(&Bs[(wc + n * 16 + lr) * 32 + lk]);
#pragma unroll
    for (int m = 0; m < 4; ++m)
#pragma unroll
      for (int n = 0; n < 4; ++n)
        acc[m][n] = __builtin_amdgcn_mfma_f32_16x16x32_bf16(af[m], bfr[n], acc[m][n], 0, 0, 0);
    __syncthreads();
  }

  int orow0 = bm * BM + wr + (lane >> 4) * 4;
  int ocol0 = bn * 128 + wc + lr;
#pragma unroll
  for (int m = 0; m < 4; ++m)
#pragma unroll
    for (int n = 0; n < 4; ++n)
#pragma unroll
      for (int j = 0; j < 4; ++j) {
        long idx = (long)(orow0 + m * 16 + j) * N + (ocol0 + n * 16);
        store_out(&C[idx], acc[m][n][j] * scale);
      }
}

// ---- single-pass causal row softmax, prefix IO (cols < (r|127)+1 only) ----
__global__ __launch_bounds__(256) void k_softmax(unsigned short* __restrict__ S, int Cc) {
  long row = blockIdx.x;
  unsigned short* s = S + row * (long)Cc;
  int r = (int)(row & (Cc - 1));
  int n = r + 1;
  int ktile = (r | 127) + 1;  // PV reads only cols < ktile
  int tid = threadIdx.x;
  int lane = tid & 63, wv = tid >> 6;
  int c0 = tid * 8;
  bool act = c0 < ktile;
  __shared__ float redm[4], reds[4];

  uint4v raw = {0, 0, 0, 0};
  if (act) raw = *reinterpret_cast<const uint4v*>(s + c0);
  float f[8];
#pragma unroll
  for (int i = 0; i < 4; ++i) {
    f[2 * i]     = b2f((unsigned short)(raw[i] & 0xFFFF));
    f[2 * i + 1] = b2f((unsigned short)(raw[i] >> 16));
  }

  float mx = -3.0e38f;
#pragma unroll
  for (int i = 0; i < 8; ++i)
    if (c0 + i < n) mx = fmaxf(mx, f[i]);
#pragma unroll
  for (int o = 32; o > 0; o >>= 1) mx = fmaxf(mx, __shfl_xor(mx, o, 64));
  if (lane == 0) redm[wv] = mx;
  __syncthreads();
  mx = fmaxf(fmaxf(redm[0], redm[1]), fmaxf(redm[2], redm[3]));

  float e[8];
  float sum = 0.f;
#pragma unroll
  for (int i = 0; i < 8; ++i) {
    e[i] = (c0 + i < n) ? __expf(f[i] - mx) : 0.f;
    sum += e[i];
  }
#pragma unroll
  for (int o = 32; o > 0; o >>= 1) sum += __shfl_xor(sum, o, 64);
  if (lane == 0) reds[wv] = sum;
  __syncthreads();
  sum = reds[0] + reds[1] + reds[2] + reds[3];
  float inv = 1.0f / sum;

  if (act) {
    uint4v out;
#pragma unroll
    for (int i = 0; i < 4; ++i) {
      unsigned lo = f2b(e[2 * i] * inv);
      unsigned hi = f2b(e[2 * i + 1] * inv);
      out[i] = lo | (hi << 16);
    }
    *reinterpret_cast<uint4v*>(s + c0) = out;
  }
}

extern "C" void kernel_launch(void* const* d_in, const int* in_sizes, int n_in,
                              void* d_out, int out_size, void* d_ws, size_t ws_size,
                              hipStream_t stream) {
  const int B = 4, C = 2048, D = 1024;
  const long MB = (long)B * C;  // 8192 rows

  const float* x  = (const float*)d_in[0];
  const float* Wq = (const float*)d_in[1];
  const float* Wk = (const float*)d_in[2];
  const float* Wv = (const float*)d_in[3];
  float* out = (float*)d_out;
  char* ws = (char*)d_ws;

  unsigned short* S   = (unsigned short*)(ws);
  unsigned short* Xb  = (unsigned short*)(ws);
  unsigned short* Wt  = (unsigned short*)(ws + 16777216);
  unsigned short* QKV = (unsigned short*)(ws + 33554432);
  unsigned short* Vt  = (unsigned short*)(ws + 83886080);
  unsigned short* Q  = QKV;
  unsigned short* Kk = QKV + MB * D;
  unsigned short* V  = QKV + 2L * MB * D;

  // 1. x -> bf16
  k_convert<<<8192, 256, 0, stream>>>(x, Xb, MB * D);

  // 2. W -> Wt (bf16, transposed), one launch
  k_transpose_w3<<<dim3(32, 32, 3), 256, 0, stream>>>(Wq, Wk, Wv, Wt);

  // 3. QKV = Xb @ Wt^T  (256^2 8-phase)
  k_gemm256<unsigned short, false, false><<<dim3(32, 4, 3), 512, 0, stream>>>(
      Xb, Wt, QKV, (int)MB, D, D, 1.0f, 0L, (long)D * D, MB * D);

  // 4. Vt[b] = V[b]^T  (32x32, conflict-free)
  k_transpose_v<<<dim3(32, 64, 4), 256, 0, stream>>>(V, Vt, C, D);

  // 5. S[b] = Q[b] @ K[b]^T / 32  (256^2 8-phase, causal tile skip)
  k_gemm256<unsigned short, true, false><<<dim3(8, 8, 4), 512, 0, stream>>>(
      Q, Kk, S, C, C, D, 1.0f / 32.0f, (long)C * D, (long)C * D, (long)C * C);

  // 6. causal softmax rows, in place (single pass, prefix IO)
  k_softmax<<<B * C, 256, 0, stream>>>(S, C);

  // 7. out[b] = P[b] @ Vt[b]^T  (128^2, K-causal, longest-first)
  k_gemm128<float, true, true><<<dim3(16, 8, 4), 256, 0, stream>>>(
      S, Vt, out, C, D, C, 1.0f, (long)C * C, (long)D * C, (long)C * D);
}